// Round 15
// baseline (2354.849 us; speedup 1.0000x reference)
//
#include <hip/hip_runtime.h>
#include <hip/hip_fp16.h>
#include <cstdint>
#include <cstddef>

#define N_NODES 100000
#define N_EDGES 3200000
#define IN_DIM  256
#define HID_DIM 64
#define OUT_DIM 32

#define NBINS      391        // ceil(100000/256), 256 nodes per bin
#define BIN_SHIFT  8
#define BIN_STRIDE 9216       // lambda=8192, +11 sigma headroom
#define BIN_EPB    8192

typedef unsigned int uint;
typedef unsigned char uchar;
typedef unsigned short ushort;

__device__ __forceinline__ float2 h2tof2(uint u) {
    __half2 h = *reinterpret_cast<const __half2*>(&u);
    return __half22float2(h);
}
__device__ __forceinline__ uint f2toh2(float a, float b) {
    __half2 h = __floats2half2_rn(a, b);
    return *reinterpret_cast<const uint*>(&h);
}
__device__ __forceinline__ ushort f2h(float a) {
    __half h = __float2half_rn(a);
    return *reinterpret_cast<const ushort*>(&h);
}

// ---------------- pass 1: bin edges by dst>>8 (packed uint) + per-node degree ----------------
__global__ __launch_bounds__(512)
void k_bin(const int* __restrict__ ei, int* __restrict__ bin_cursor,
           uint* __restrict__ binned, int* __restrict__ deg) {
    __shared__ int   lcount[NBINS];
    __shared__ int   lstart[NBINS];
    __shared__ int   lplace[NBINS];
    __shared__ int   gbase[NBINS];
    __shared__ int   sc[512];
    __shared__ uint  stage[BIN_EPB];    // 32 KB
    __shared__ uchar binid[BIN_EPB];    //  8 KB

    const int tid  = threadIdx.x;
    const int bid  = blockIdx.x;

    const int e0   = bid * BIN_EPB;
    const int nval = min(BIN_EPB, N_EDGES - e0);

    for (int i = tid; i < NBINS; i += 512) lcount[i] = 0;
    __syncthreads();

    #pragma unroll
    for (int k = 0; k < BIN_EPB / 512; ++k) {
        int e = e0 + k * 512 + tid;
        if (e < N_EDGES) {
            int d = ei[N_EDGES + e];
            atomicAdd(&lcount[d >> BIN_SHIFT], 1);
            atomicAdd(&deg[d], 1);           // global degree (fire-and-forget)
        }
    }
    __syncthreads();

    int v = (tid < NBINS) ? lcount[tid] : 0;
    sc[tid] = v; __syncthreads();
    for (int off = 1; off < 512; off <<= 1) {
        int x = sc[tid];
        if (tid >= off) x += sc[tid - off];
        __syncthreads(); sc[tid] = x; __syncthreads();
    }
    if (tid < NBINS) {
        int excl = sc[tid] - v;
        lstart[tid] = excl;
        lplace[tid] = excl;
        gbase[tid]  = atomicAdd(&bin_cursor[tid], v);
    }
    __syncthreads();

    #pragma unroll
    for (int k = 0; k < BIN_EPB / 512; ++k) {
        int e = e0 + k * 512 + tid;
        if (e < N_EDGES) {
            int s = ei[e];
            int d = ei[N_EDGES + e];
            int b = d >> BIN_SHIFT;
            int p = atomicAdd(&lplace[b], 1);
            stage[p] = (uint)s | ((uint)(d & 255) << 17) | ((uint)(b >> 8) << 25);
            binid[p] = (uchar)(b & 255);
        }
    }
    __syncthreads();

    for (int i = tid; i < nval; i += 512) {
        uint ed = stage[i];
        int  b  = (int)binid[i] | (int)((ed >> 25) & 1u) << 8;
        int  gix = gbase[b] + (i - lstart[b]);
        if (gix < BIN_STRIDE)
            binned[(size_t)b * BIN_STRIDE + gix] = ed;
    }
}

// ---------------- dn = rsqrt(deg+1) ----------------
__global__ __launch_bounds__(512)
void k_dn(const int* __restrict__ deg, float* __restrict__ dn) {
    int n = blockIdx.x * 512 + threadIdx.x;
    if (n < N_NODES) dn[n] = rsqrtf((float)deg[n] + 1.0f);
}

// ---------------- tiled fp32 GEMM: Y[M,NC] = X[M,KD] @ W[KD,NC], fp16 output ----------------
template<int KD, int NC>
__global__ __launch_bounds__(32 * (NC / 8))
void k_gemm_h(const float* __restrict__ X, const float* __restrict__ W,
              uint* __restrict__ Yh, int M) {
    constexpr int TC = NC / 8;
    constexpr int THREADS = 32 * TC;
    constexpr int KC = 32;
    __shared__ float Xs[128][33];
    __shared__ float Ws[KC][NC];

    const int tid  = threadIdx.x;
    const int tr   = tid / TC;
    const int tc   = tid % TC;
    const int row0 = blockIdx.x * 128;

    float acc[4][8];
    #pragma unroll
    for (int i = 0; i < 4; ++i)
        #pragma unroll
        for (int j = 0; j < 8; ++j) acc[i][j] = 0.f;

    for (int kc = 0; kc < KD; kc += KC) {
        #pragma unroll
        for (int i = tid; i < 128 * (KC / 4); i += THREADS) {
            int r  = i / (KC / 4);
            int k4 = (i % (KC / 4)) * 4;
            float4 v = make_float4(0.f, 0.f, 0.f, 0.f);
            int gr = row0 + r;
            if (gr < M)
                v = *reinterpret_cast<const float4*>(&X[(size_t)gr * KD + kc + k4]);
            Xs[r][k4 + 0] = v.x; Xs[r][k4 + 1] = v.y;
            Xs[r][k4 + 2] = v.z; Xs[r][k4 + 3] = v.w;
        }
        #pragma unroll
        for (int i = tid; i < KC * (NC / 4); i += THREADS) {
            int kk = i / (NC / 4);
            int c4 = (i % (NC / 4)) * 4;
            *reinterpret_cast<float4*>(&Ws[kk][c4]) =
                *reinterpret_cast<const float4*>(&W[(size_t)(kc + kk) * NC + c4]);
        }
        __syncthreads();

        #pragma unroll
        for (int kk = 0; kk < KC; ++kk) {
            float xv[4];
            #pragma unroll
            for (int i = 0; i < 4; ++i) xv[i] = Xs[tr * 4 + i][kk];
            float4 w0 = *reinterpret_cast<const float4*>(&Ws[kk][tc * 8]);
            float4 w1 = *reinterpret_cast<const float4*>(&Ws[kk][tc * 8 + 4]);
            float wv[8] = {w0.x, w0.y, w0.z, w0.w, w1.x, w1.y, w1.z, w1.w};
            #pragma unroll
            for (int i = 0; i < 4; ++i)
                #pragma unroll
                for (int j = 0; j < 8; ++j)
                    acc[i][j] = fmaf(xv[i], wv[j], acc[i][j]);
        }
        __syncthreads();
    }

    #pragma unroll
    for (int i = 0; i < 4; ++i) {
        int gr = row0 + tr * 4 + i;
        if (gr < M) {
            uint4 o;
            o.x = f2toh2(acc[i][0], acc[i][1]);
            o.y = f2toh2(acc[i][2], acc[i][3]);
            o.z = f2toh2(acc[i][4], acc[i][5]);
            o.w = f2toh2(acc[i][6], acc[i][7]);
            *reinterpret_cast<uint4*>(&Yh[(size_t)gr * (NC / 2) + tc * 4]) = o;
        }
    }
}

// ---------------- agg1 block-per-bin: LDS fp32 accumulate + fused GEMM2 -> H2 ----------------
// Each block owns one 256-node bin; waves walk the bin's binned[] segment,
// 2 edges per wave-op (slot = lane>>5), lane&31 = fp16-pair of the row.
// Feature f stored at LDS idx (f>>1) + (f&1)*32 (bank spread). Per-(node,feature)
// sum = single LDS location, atomic-permuted order (same class as prior rounds).
__global__ __launch_bounds__(512)
void k_agg1b(const uint* __restrict__ binned, const int* __restrict__ bin_cursor,
             const uint* __restrict__ H1h, const float* __restrict__ dn,
             const float* __restrict__ b1, const float* __restrict__ W2,
             ushort* __restrict__ H2h) {
    __shared__ float accs[256 * 64];   // exactly 64 KB

    const int tid  = threadIdx.x;
    const int b    = blockIdx.x;
    const int n0   = b << BIN_SHIFT;
    const int cnt  = min(bin_cursor[b], BIN_STRIDE);
    const uint* bb = binned + (size_t)b * BIN_STRIDE;

    const int wave = tid >> 6, lane = tid & 63;
    const int slot = lane >> 5;        // 0/1 -> which edge of the pair
    const int l    = lane & 31;        // uint index within 32-uint row

    // W2 column in registers: lane c=lane&31 holds rows hh*32..hh*32+31
    const int c = lane & 31, hh = lane >> 5;
    float w2r[32];
    #pragma unroll
    for (int fi = 0; fi < 32; ++fi)
        w2r[fi] = W2[(hh * 32 + fi) * OUT_DIM + c];

    for (int i = tid; i < 256 * 64; i += 512) accs[i] = 0.f;
    __syncthreads();

    const int npairs = (cnt + 1) >> 1;
    for (int p0 = wave; p0 < npairs; p0 += 32) {
        uint vv[4]; float ds[4]; int dl[4];
        #pragma unroll
        for (int k = 0; k < 4; ++k) {
            int p  = p0 + 8 * k;
            int e  = 2 * p + slot;
            bool ok = (e < cnt);
            uint edv = bb[ok ? e : 0];
            int  s   = (int)(edv & 0x1FFFFu);
            dl[k]    = (int)((edv >> 17) & 255u);
            ds[k]    = ok ? dn[s] : 0.f;
            vv[k]    = H1h[(size_t)s * 32 + l];
        }
        #pragma unroll
        for (int k = 0; k < 4; ++k) {
            float2 vf = h2tof2(vv[k]);
            atomicAdd(&accs[dl[k] * 64 + l],      ds[k] * vf.x);   // feature 2l
            atomicAdd(&accs[dl[k] * 64 + 32 + l], ds[k] * vf.y);   // feature 2l+1
        }
    }
    __syncthreads();

    // epilogue: wave takes nodes nn = wave, wave+8, ...; lane = feature f
    const int f = lane;
    for (int nn = wave; nn < 256; nn += 8) {
        int n = n0 + nn;
        if (n >= N_NODES) continue;
        float dnn = dn[n];
        uint  su  = H1h[(size_t)n * 32 + (f >> 1)];
        float2 sf = h2tof2(su);
        float selfv = (f & 1) ? sf.y : sf.x;
        float a = accs[nn * 64 + (f >> 1) + (f & 1) * 32];
        float o = fmaxf(b1[f] + dnn * fmaf(dnn, selfv, a), 0.f);

        // fused GEMM2 (r5 association): c-th col, halves split f-range ascending
        float acc2 = 0.f;
        #pragma unroll
        for (int fi = 0; fi < 32; ++fi) {
            int fg = hh * 32 + fi;
            float vvv = __shfl(o, fg);
            acc2 = fmaf(vvv, w2r[fi], acc2);
        }
        acc2 += __shfl_xor(acc2, 32);
        if (hh == 0) H2h[(size_t)n * 32 + c] = f2h(acc2);
    }
}

// ---------------- agg2 block-per-bin: LDS accumulate + fused MLP head ----------------
// 4 edges per wave-op (slot = lane>>4), lane&15 = fp16-pair of the 16-uint row.
// acc stride 33 floats/node (bank spread); feature f at idx (f>>1)+(f&1)*16.
__global__ __launch_bounds__(512)
void k_agg2b(const uint* __restrict__ binned, const int* __restrict__ bin_cursor,
             const uint* __restrict__ H2h, const float* __restrict__ dn,
             const float* __restrict__ b2, const float* __restrict__ Wp1,
             const float* __restrict__ bp1, const float* __restrict__ Wp2,
             const float* __restrict__ bp2, float* __restrict__ out_h,
             float* __restrict__ out_w) {
    __shared__ float acc2s[256 * 33];  // 33.8 KB
    __shared__ float Wp1s[OUT_DIM * HID_DIM];
    __shared__ float Wp2s[HID_DIM];
    __shared__ float bp1s[HID_DIM];

    const int tid  = threadIdx.x;
    const int b    = blockIdx.x;
    const int n0   = b << BIN_SHIFT;
    const int cnt  = min(bin_cursor[b], BIN_STRIDE);
    const uint* bb = binned + (size_t)b * BIN_STRIDE;

    for (int i = tid; i < OUT_DIM * HID_DIM; i += 512) Wp1s[i] = Wp1[i];
    if (tid < HID_DIM) { Wp2s[tid] = Wp2[tid]; bp1s[tid] = bp1[tid]; }
    for (int i = tid; i < 256 * 33; i += 512) acc2s[i] = 0.f;
    __syncthreads();

    const int wave = tid >> 6, lane = tid & 63;
    const int slot = lane >> 4;        // 0..3
    const int l    = lane & 15;        // uint index within 16-uint row

    const int nquads = (cnt + 3) >> 2;
    for (int q0 = wave; q0 < nquads; q0 += 32) {
        uint vv[4]; float ds[4]; int dl[4];
        #pragma unroll
        for (int k = 0; k < 4; ++k) {
            int q  = q0 + 8 * k;
            int e  = 4 * q + slot;
            bool ok = (e < cnt);
            uint edv = bb[ok ? e : 0];
            int  s   = (int)(edv & 0x1FFFFu);
            dl[k]    = (int)((edv >> 17) & 255u);
            ds[k]    = ok ? dn[s] : 0.f;
            vv[k]    = H2h[(size_t)s * 16 + l];
        }
        #pragma unroll
        for (int k = 0; k < 4; ++k) {
            float2 vf = h2tof2(vv[k]);
            atomicAdd(&acc2s[dl[k] * 33 + l],      ds[k] * vf.x);  // feature 2l
            atomicAdd(&acc2s[dl[k] * 33 + 16 + l], ds[k] * vf.y);  // feature 2l+1
        }
    }
    __syncthreads();

    // epilogue: wave takes nodes nn = wave, wave+8, ...
    for (int nn = wave; nn < 256; nn += 8) {
        int n = n0 + nn;
        if (n >= N_NODES) continue;
        float dnn = dn[n];
        float hvv = 0.f;
        if (lane < 32) {
            uint  su  = H2h[(size_t)n * 16 + (lane >> 1)];
            float2 sf = h2tof2(su);
            float selfv = (lane & 1) ? sf.y : sf.x;
            float a = acc2s[nn * 33 + (lane >> 1) + (lane & 1) * 16];
            hvv = b2[lane] + dnn * fmaf(dnn, selfv, a);
            out_h[(size_t)n * OUT_DIM + lane] = hvv;
        }
        // MLP (r5 association): p[j] = relu(bp1[j] + sum_ff h_ff Wp1[ff][j])
        float p = bp1s[lane];
        #pragma unroll
        for (int ff = 0; ff < 32; ++ff) {
            float hf = __shfl(hvv, ff);
            p = fmaf(hf, Wp1s[ff * HID_DIM + lane], p);
        }
        p = fmaxf(p, 0.f);
        float z = p * Wp2s[lane];
        #pragma unroll
        for (int off = 32; off; off >>= 1) z += __shfl_xor(z, off);
        if (lane == 0) out_w[n] = 1.f / (1.f + __expf(-(z + bp2[0])));
    }
}

// ---------------- launcher ----------------
extern "C" void kernel_launch(void* const* d_in, const int* in_sizes, int n_in,
                              void* d_out, int out_size, void* d_ws, size_t ws_size,
                              hipStream_t stream) {
    const float* x   = (const float*)d_in[0];
    const int*   ei  = (const int*)d_in[1];
    const float* W1  = (const float*)d_in[2];
    const float* b1  = (const float*)d_in[3];
    const float* W2  = (const float*)d_in[4];
    const float* b2  = (const float*)d_in[5];
    const float* Wp1 = (const float*)d_in[6];
    const float* bp1 = (const float*)d_in[7];
    const float* Wp2 = (const float*)d_in[8];
    const float* bp2 = (const float*)d_in[9];
    float* out = (float*)d_out;

    char* ws = (char*)d_ws;
    // binned = NBINS*BIN_STRIDE*4 = 14,413,824 B (slot count, not edge count!)
    int*    bin_cursor = (int*)   (ws + 0);          //  1,564 B
    int*    deg        = (int*)   (ws + 2048);       //  400,000 B -> ends 402,048
    float*  dn         = (float*) (ws + 402176);     //  400,000 B -> ends 802,176
    uint*   binned     = (uint*)  (ws + 802304);     //  14,413,824 B -> ends 15,216,128
    uint*   H1h        = (uint*)  (ws + 15216128);   //  12,800,000 B -> ends 28,016,128
    uint*   H2h        = (uint*)  (ws + 28016128);   //   6,400,000 B -> ends 34,416,128

    // zero bin_cursor + deg in one shot (covers the pad too)
    hipMemsetAsync(ws, 0, 402048, stream);

    k_bin<<<(N_EDGES + BIN_EPB - 1) / BIN_EPB, 512, 0, stream>>>(ei, bin_cursor,
                                                                 binned, deg);
    k_dn<<<(N_NODES + 511) / 512, 512, 0, stream>>>(deg, dn);
    k_gemm_h<IN_DIM, HID_DIM><<<(N_NODES + 127) / 128, 256, 0, stream>>>(x, W1, H1h, N_NODES);

    k_agg1b<<<NBINS, 512, 0, stream>>>(binned, bin_cursor, H1h, dn, b1, W2,
                                       (ushort*)H2h);
    k_agg2b<<<NBINS, 512, 0, stream>>>(binned, bin_cursor, H2h, dn, b2,
                                       Wp1, bp1, Wp2, bp2,
                                       out, out + (size_t)N_NODES * OUT_DIM);
}

// Round 16
// 278.428 us; speedup vs baseline: 8.4577x; 8.4577x over previous
//
#include <hip/hip_runtime.h>
#include <hip/hip_fp16.h>
#include <cstdint>
#include <cstddef>

#define N_NODES 100000
#define N_EDGES 3200000
#define IN_DIM  256
#define HID_DIM 64
#define OUT_DIM 32

#define NBINS      391        // ceil(100000/256), 256 nodes per bin
#define BIN_SHIFT  8
#define BIN_STRIDE 9216       // lambda=8192, +11 sigma headroom
#define BIN_EPB    8192

typedef unsigned int uint;
typedef unsigned char uchar;
typedef unsigned short ushort;

__device__ __forceinline__ float2 h2tof2(uint u) {
    __half2 h = *reinterpret_cast<const __half2*>(&u);
    return __half22float2(h);
}
__device__ __forceinline__ uint f2toh2(float a, float b) {
    __half2 h = __floats2half2_rn(a, b);
    return *reinterpret_cast<const uint*>(&h);
}
__device__ __forceinline__ ushort f2h(float a) {
    __half h = __float2half_rn(a);
    return *reinterpret_cast<const ushort*>(&h);
}
// acc = fma(w, (float)fp16_lo/hi(v), acc) — exact cvt, bit-identical to cvt+fmaf.
__device__ __forceinline__ void fma_mix_lo(float& acc, float w, uint v) {
    asm("v_fma_mix_f32 %0, %1, %2, %0 op_sel:[0,0,0] op_sel_hi:[0,1,0]"
        : "+v"(acc) : "v"(w), "v"(v));
}
__device__ __forceinline__ void fma_mix_hi(float& acc, float w, uint v) {
    asm("v_fma_mix_f32 %0, %1, %2, %0 op_sel:[0,1,0] op_sel_hi:[0,1,0]"
        : "+v"(acc) : "v"(w), "v"(v));
}

// ---------------- pass 1: bin edges by dst>>8 (packed uint), inline last-block scan ----------------
// Global-load loops batched 4-deep (latency fix; loads issued together).
__global__ __launch_bounds__(512)
void k_bin(const int* __restrict__ ei, int* __restrict__ bin_cursor,
           uint* __restrict__ binned, int* __restrict__ bin_base,
           int* __restrict__ rowptr) {
    __shared__ int   lcount[NBINS];
    __shared__ int   lstart[NBINS];
    __shared__ int   lplace[NBINS];
    __shared__ int   gbase[NBINS];
    __shared__ int   sc[512];
    __shared__ uint  stage[BIN_EPB];    // 32 KB
    __shared__ uchar binid[BIN_EPB];    //  8 KB

    const int tid  = threadIdx.x;
    const int bid  = blockIdx.x;
    int*      done = bin_cursor + NBINS;   // zeroed by memset

    const int e0   = bid * BIN_EPB;
    const int nval = min(BIN_EPB, N_EDGES - e0);

    for (int i = tid; i < NBINS; i += 512) lcount[i] = 0;
    __syncthreads();

    // count pass: 16 edges/thread, batched 4-deep
    #pragma unroll
    for (int k = 0; k < BIN_EPB / 512; k += 4) {
        int d4[4];
        #pragma unroll
        for (int u = 0; u < 4; ++u) {
            int e = e0 + (k + u) * 512 + tid;
            d4[u] = (e < N_EDGES) ? ei[N_EDGES + e] : -1;
        }
        #pragma unroll
        for (int u = 0; u < 4; ++u)
            if (d4[u] >= 0) atomicAdd(&lcount[d4[u] >> BIN_SHIFT], 1);
    }
    __syncthreads();

    int v = (tid < NBINS) ? lcount[tid] : 0;
    sc[tid] = v; __syncthreads();
    for (int off = 1; off < 512; off <<= 1) {
        int x = sc[tid];
        if (tid >= off) x += sc[tid - off];
        __syncthreads(); sc[tid] = x; __syncthreads();
    }
    if (tid < NBINS) {
        int excl = sc[tid] - v;
        lstart[tid] = excl;
        lplace[tid] = excl;
        gbase[tid]  = atomicAdd(&bin_cursor[tid], v);
    }
    __syncthreads();

    // stage pass: batched 4-deep loads of (s,d)
    #pragma unroll
    for (int k = 0; k < BIN_EPB / 512; k += 4) {
        int s4[4], d4[4];
        #pragma unroll
        for (int u = 0; u < 4; ++u) {
            int e = e0 + (k + u) * 512 + tid;
            bool ok = (e < N_EDGES);
            s4[u] = ok ? ei[e] : -1;
            d4[u] = ok ? ei[N_EDGES + e] : 0;
        }
        #pragma unroll
        for (int u = 0; u < 4; ++u) {
            if (s4[u] >= 0) {
                int b = d4[u] >> BIN_SHIFT;
                int p = atomicAdd(&lplace[b], 1);
                stage[p] = (uint)s4[u] | ((uint)(d4[u] & 255) << 17)
                         | ((uint)(b >> 8) << 25);
                binid[p] = (uchar)(b & 255);
            }
        }
    }
    __syncthreads();

    for (int i = tid; i < nval; i += 512) {
        uint ed = stage[i];
        int  b  = (int)binid[i] | (int)((ed >> 25) & 1u) << 8;
        int  gix = gbase[b] + (i - lstart[b]);
        if (gix < BIN_STRIDE)
            binned[(size_t)b * BIN_STRIDE + gix] = ed;
    }
    __syncthreads();

    // ---- last-block inline binscan ----
    if (tid == 0) {
        __threadfence();
        lcount[0] = (atomicAdd(done, 1) == gridDim.x - 1) ? 1 : 0;
    }
    __syncthreads();
    if (lcount[0]) {
        int t = tid;
        int vv = 0;
        if (t < NBINS) vv = min(atomicAdd(&bin_cursor[t], 0), BIN_STRIDE);
        sc[t] = vv; __syncthreads();
        for (int off = 1; off < 512; off <<= 1) {
            int x = sc[t];
            if (t >= off) x += sc[t - off];
            __syncthreads(); sc[t] = x; __syncthreads();
        }
        if (t < NBINS)      bin_base[t] = sc[t] - vv;
        if (t == NBINS - 1) rowptr[N_NODES] = sc[t];
    }
}

// ---------------- pass 2: per-bin LDS counting sort -> CSR (+dn), 512 thr, batched ----------------
__global__ __launch_bounds__(512)
void k_csr(const uint* __restrict__ binned, const int* __restrict__ bin_cursor,
           const int* __restrict__ bin_base, int* __restrict__ rowptr,
           float* __restrict__ dn, int* __restrict__ csr) {
    __shared__ int lcnt[256];
    __shared__ int lpl[256];
    __shared__ int sc[256];
    __shared__ int csr_s[BIN_STRIDE];   // 36.9 KB

    const int tid   = threadIdx.x;
    const int b     = blockIdx.x;
    const int n0    = b << BIN_SHIFT;
    const int cnt   = min(bin_cursor[b], BIN_STRIDE);
    const int ebase = bin_base[b];
    const uint* bb  = binned + (size_t)b * BIN_STRIDE;

    if (tid < 256) lcnt[tid] = 0;
    __syncthreads();

    // count pass, 4-deep batched loads
    for (int i0 = tid; i0 < cnt; i0 += 2048) {
        uint e4[4]; int ok[4];
        #pragma unroll
        for (int u = 0; u < 4; ++u) {
            int i = i0 + u * 512;
            ok[u] = (i < cnt);
            e4[u] = bb[ok[u] ? i : 0];
        }
        #pragma unroll
        for (int u = 0; u < 4; ++u)
            if (ok[u]) atomicAdd(&lcnt[(e4[u] >> 17) & 255u], 1);
    }
    __syncthreads();

    int v = 0;
    if (tid < 256) { v = lcnt[tid]; sc[tid] = v; }
    __syncthreads();
    for (int off = 1; off < 256; off <<= 1) {
        int x = 0;
        if (tid < 256) { x = sc[tid]; if (tid >= off) x += sc[tid - off]; }
        __syncthreads();
        if (tid < 256) sc[tid] = x;
        __syncthreads();
    }
    if (tid < 256) {
        int excl = sc[tid] - v;
        lpl[tid] = excl;
        int n = n0 + tid;
        if (n < N_NODES) {
            rowptr[n] = ebase + excl;
            dn[n]     = rsqrtf((float)v + 1.0f);   // +1 self-loop
        }
    }
    __syncthreads();

    // placement pass, 4-deep batched loads
    for (int i0 = tid; i0 < cnt; i0 += 2048) {
        uint e4[4]; int ok[4];
        #pragma unroll
        for (int u = 0; u < 4; ++u) {
            int i = i0 + u * 512;
            ok[u] = (i < cnt);
            e4[u] = bb[ok[u] ? i : 0];
        }
        #pragma unroll
        for (int u = 0; u < 4; ++u) {
            if (ok[u]) {
                int p = atomicAdd(&lpl[(e4[u] >> 17) & 255u], 1);
                csr_s[p] = (int)(e4[u] & 0x1FFFFu);
            }
        }
    }
    __syncthreads();
    for (int i = tid; i < cnt; i += 512)
        csr[ebase + i] = csr_s[i];
}

// ---------------- tiled fp32 GEMM: Y[M,NC] = X[M,KD] @ W[KD,NC], fp16 output ----------------
template<int KD, int NC>
__global__ __launch_bounds__(32 * (NC / 8))
void k_gemm_h(const float* __restrict__ X, const float* __restrict__ W,
              uint* __restrict__ Yh, int M) {
    constexpr int TC = NC / 8;
    constexpr int THREADS = 32 * TC;
    constexpr int KC = 32;
    __shared__ float Xs[128][33];
    __shared__ float Ws[KC][NC];

    const int tid  = threadIdx.x;
    const int tr   = tid / TC;
    const int tc   = tid % TC;
    const int row0 = blockIdx.x * 128;

    float acc[4][8];
    #pragma unroll
    for (int i = 0; i < 4; ++i)
        #pragma unroll
        for (int j = 0; j < 8; ++j) acc[i][j] = 0.f;

    for (int kc = 0; kc < KD; kc += KC) {
        #pragma unroll
        for (int i = tid; i < 128 * (KC / 4); i += THREADS) {
            int r  = i / (KC / 4);
            int k4 = (i % (KC / 4)) * 4;
            float4 v = make_float4(0.f, 0.f, 0.f, 0.f);
            int gr = row0 + r;
            if (gr < M)
                v = *reinterpret_cast<const float4*>(&X[(size_t)gr * KD + kc + k4]);
            Xs[r][k4 + 0] = v.x; Xs[r][k4 + 1] = v.y;
            Xs[r][k4 + 2] = v.z; Xs[r][k4 + 3] = v.w;
        }
        #pragma unroll
        for (int i = tid; i < KC * (NC / 4); i += THREADS) {
            int kk = i / (NC / 4);
            int c4 = (i % (NC / 4)) * 4;
            *reinterpret_cast<float4*>(&Ws[kk][c4]) =
                *reinterpret_cast<const float4*>(&W[(size_t)(kc + kk) * NC + c4]);
        }
        __syncthreads();

        #pragma unroll
        for (int kk = 0; kk < KC; ++kk) {
            float xv[4];
            #pragma unroll
            for (int i = 0; i < 4; ++i) xv[i] = Xs[tr * 4 + i][kk];
            float4 w0 = *reinterpret_cast<const float4*>(&Ws[kk][tc * 8]);
            float4 w1 = *reinterpret_cast<const float4*>(&Ws[kk][tc * 8 + 4]);
            float wv[8] = {w0.x, w0.y, w0.z, w0.w, w1.x, w1.y, w1.z, w1.w};
            #pragma unroll
            for (int i = 0; i < 4; ++i)
                #pragma unroll
                for (int j = 0; j < 8; ++j)
                    acc[i][j] = fmaf(xv[i], wv[j], acc[i][j]);
        }
        __syncthreads();
    }

    #pragma unroll
    for (int i = 0; i < 4; ++i) {
        int gr = row0 + tr * 4 + i;
        if (gr < M) {
            uint4 o;
            o.x = f2toh2(acc[i][0], acc[i][1]);
            o.y = f2toh2(acc[i][2], acc[i][3]);
            o.z = f2toh2(acc[i][4], acc[i][5]);
            o.w = f2toh2(acc[i][6], acc[i][7]);
            *reinterpret_cast<uint4*>(&Yh[(size_t)gr * (NC / 2) + tc * 4]) = o;
        }
    }
}

// ---------------- agg1 (+bias+relu) fused with GEMM2 -> H2 (fp16) ----------------
// TWO nodes per wave (r12/r14 verbatim, passing); fp16x2 gathers; fp32 accum
// via v_fma_mix. Per-feature chain: self first, edges ascending in CSR order,
// single accumulator; idle slots exact fma(0,.).
__global__ __launch_bounds__(256)
void k_agg1(const uint* __restrict__ H1h, const int* __restrict__ rowptr,
            const int* __restrict__ csr, const float* __restrict__ dn,
            const float* __restrict__ b1, const float* __restrict__ W2,
            ushort* __restrict__ H2h) {
    __shared__ float W2s[HID_DIM * OUT_DIM];   // 8 KB
    for (int i = threadIdx.x; i < HID_DIM * OUT_DIM; i += 256) W2s[i] = W2[i];
    __syncthreads();

    int wid  = (blockIdx.x * blockDim.x + threadIdx.x) >> 6;
    int lane = threadIdx.x & 63;
    if (wid >= N_NODES / 2) return;
    const int half = lane >> 5;
    const int hb   = half << 5;
    const int l    = lane & 31;
    const int n    = 2 * wid + half;

    int rp = (l < 2) ? rowptr[n + l] : 0;
    int base = __shfl(rp, hb + 0);
    int cnt  = __shfl(rp, hb + 1) - base;
    const float dnn = dn[n];

    float2 self2 = h2tof2(H1h[(size_t)n * 32 + l]);
    float2 acc;
    acc.x = dnn * self2.x;
    acc.y = dnn * self2.y;

    const int cnt2 = max(cnt, __shfl_xor(cnt, 32));
    for (int b0 = 0; b0 < cnt2; b0 += 32) {
        int m_own = min(32, cnt - b0);
        int m_max = min(32, cnt2 - b0);
        int s = 0; float dsv = 0.f;
        if (l < m_own) { s = csr[base + b0 + l]; dsv = dn[s]; }
        for (int j0 = 0; j0 < m_max; j0 += 8) {
            uint v[8]; float w[8];
            #pragma unroll
            for (int i = 0; i < 8; ++i) {
                int j  = j0 + i;
                int sj = __shfl(s, hb + j);
                w[i] = __shfl(dsv, hb + j);
                v[i] = H1h[(size_t)sj * 32 + l];
            }
            #pragma unroll
            for (int i = 0; i < 8; ++i) {
                fma_mix_lo(acc.x, w[i], v[i]);
                fma_mix_hi(acc.y, w[i], v[i]);
            }
        }
    }
    float2 b1q = *reinterpret_cast<const float2*>(b1 + 2 * l);
    float2 o;
    o.x = fmaxf(b1q.x + dnn * acc.x, 0.f);
    o.y = fmaxf(b1q.y + dnn * acc.y, 0.f);

    const int c = lane & 31, hh = lane >> 5;
    #pragma unroll
    for (int nodesel = 0; nodesel < 2; ++nodesel) {
        const int nb = nodesel << 5;
        float acc2 = 0.f;
        #pragma unroll
        for (int fi = 0; fi < 32; ++fi) {
            int f = hh * 32 + fi;
            float vv = (f & 1) ? __shfl(o.y, nb + (f >> 1))
                               : __shfl(o.x, nb + (f >> 1));
            acc2 = fmaf(vv, W2s[f * OUT_DIM + c], acc2);
        }
        acc2 += __shfl_xor(acc2, 32);
        if (hh == 0) H2h[(size_t)(2 * wid + nodesel) * 32 + c] = f2h(acc2);
    }
}

// ---------------- agg2 (+bias) fused with MLP head ----------------
// TWO nodes per wave (r12/r14 verbatim, passing), fp16x2 gathers + fma_mix.
__global__ __launch_bounds__(256)
void k_agg2m(const uint* __restrict__ H2h, const int* __restrict__ rowptr,
             const int* __restrict__ csr, const float* __restrict__ dn,
             const float* __restrict__ b2, const float* __restrict__ Wp1,
             const float* __restrict__ bp1, const float* __restrict__ Wp2,
             const float* __restrict__ bp2, float* __restrict__ out_h,
             float* __restrict__ out_w) {
    __shared__ float Wp1s[OUT_DIM * HID_DIM];  // 8 KB
    __shared__ float Wp2s[HID_DIM];
    __shared__ float bp1s[HID_DIM];
    for (int i = threadIdx.x; i < OUT_DIM * HID_DIM; i += 256) Wp1s[i] = Wp1[i];
    if (threadIdx.x < HID_DIM) {
        Wp2s[threadIdx.x] = Wp2[threadIdx.x];
        bp1s[threadIdx.x] = bp1[threadIdx.x];
    }
    __syncthreads();

    int wid  = (blockIdx.x * blockDim.x + threadIdx.x) >> 6;
    int lane = threadIdx.x & 63;
    if (wid >= N_NODES / 2) return;
    const int nd  = lane >> 5;
    const int nb0 = nd << 5;
    const int l32 = lane & 31;
    const int l   = lane & 15;
    const int h2  = (lane >> 4) & 1;
    const int n   = 2 * wid + nd;

    int rp = (lane < 3) ? rowptr[2 * wid + lane] : 0;
    int base = __shfl(rp, nd);
    int cnt  = __shfl(rp, nd + 1) - base;
    const float dnn = dn[n];

    float2 self2 = h2tof2(H2h[(size_t)n * 16 + l]);
    float2 acc;
    acc.x = (h2 == 0) ? dnn * self2.x : 0.f;
    acc.y = (h2 == 0) ? dnn * self2.y : 0.f;

    const int cnt2 = max(cnt, __shfl_xor(cnt, 32));
    for (int b0 = 0; b0 < cnt2; b0 += 32) {
        int m_own = min(32, cnt - b0);
        int m_max = min(32, cnt2 - b0);
        int s = 0; float dsv = 0.f;
        if (l32 < m_own) { s = csr[base + b0 + l32]; dsv = dn[s]; }
        for (int j0 = h2; j0 < m_max; j0 += 16) {
            uint v[8]; float w[8];
            #pragma unroll
            for (int i = 0; i < 8; ++i) {
                int j  = j0 + 2 * i;              // <= j0+14 <= 31
                int sj = __shfl(s, nb0 + j);
                w[i] = __shfl(dsv, nb0 + j);      // 0 when j >= m_own
                v[i] = H2h[(size_t)sj * 16 + l];
            }
            #pragma unroll
            for (int i = 0; i < 8; ++i) {
                fma_mix_lo(acc.x, w[i], v[i]);
                fma_mix_hi(acc.y, w[i], v[i]);
            }
        }
    }
    acc.x += __shfl_xor(acc.x, 16);               // even + odd (r5 association)
    acc.y += __shfl_xor(acc.y, 16);
    float2 b2q = *reinterpret_cast<const float2*>(b2 + 2 * l);
    float2 hv;
    hv.x = b2q.x + dnn * acc.x;
    hv.y = b2q.y + dnn * acc.y;
    if (h2 == 0)
        *reinterpret_cast<float2*>(out_h + (size_t)n * OUT_DIM + 2 * l) = hv;

    // MLP head per node: p[j]=relu(bp1[j]+sum_ff h_ff Wp1[ff][j])
    #pragma unroll
    for (int nodesel = 0; nodesel < 2; ++nodesel) {
        const int nb = nodesel << 5;
        float p = bp1s[lane];
        #pragma unroll
        for (int ff = 0; ff < OUT_DIM; ++ff) {
            float hf = (ff & 1) ? __shfl(hv.y, nb + (ff >> 1))
                                : __shfl(hv.x, nb + (ff >> 1));
            p = fmaf(hf, Wp1s[ff * HID_DIM + lane], p);
        }
        p = fmaxf(p, 0.f);
        float z = p * Wp2s[lane];
        #pragma unroll
        for (int off = 32; off; off >>= 1) z += __shfl_xor(z, off);
        if (lane == 0)
            out_w[2 * wid + nodesel] = 1.f / (1.f + __expf(-(z + bp2[0])));
    }
}

// ---------------- launcher ----------------
extern "C" void kernel_launch(void* const* d_in, const int* in_sizes, int n_in,
                              void* d_out, int out_size, void* d_ws, size_t ws_size,
                              hipStream_t stream) {
    const float* x   = (const float*)d_in[0];
    const int*   ei  = (const int*)d_in[1];
    const float* W1  = (const float*)d_in[2];
    const float* b1  = (const float*)d_in[3];
    const float* W2  = (const float*)d_in[4];
    const float* b2  = (const float*)d_in[5];
    const float* Wp1 = (const float*)d_in[6];
    const float* bp1 = (const float*)d_in[7];
    const float* Wp2 = (const float*)d_in[8];
    const float* bp2 = (const float*)d_in[9];
    float* out = (float*)d_out;

    char* ws = (char*)d_ws;
    // binned = NBINS*BIN_STRIDE*4 = 14,413,824 B (slot count, not edge count!)
    int*    bin_cursor = (int*)   (ws + 0);          //  1,568 B (incl. done ctr)
    int*    bin_base   = (int*)   (ws + 2048);       //  1,564 B
    int*    rowptr     = (int*)   (ws + 4096);       //  400,004 B
    float*  dn         = (float*) (ws + 404480);     //  400,000 B
    int*    csr        = (int*)   (ws + 804608);     //  12,800,000 B -> ends 13,604,608
    uint*   binned     = (uint*)  (ws + 13604608);   //  14,413,824 B -> ends 28,018,432
    uint*   H1h        = (uint*)  (ws + 28018432);   //  12,800,000 B -> ends 40,818,432
    ushort* H2h        = (ushort*)(ws + 40818432);   //   6,400,000 B -> ends 47,218,432

    hipMemsetAsync(bin_cursor, 0, (NBINS + 1) * sizeof(int), stream);

    k_bin<<<(N_EDGES + BIN_EPB - 1) / BIN_EPB, 512, 0, stream>>>(ei, bin_cursor, binned,
                                                                 bin_base, rowptr);
    k_csr<<<NBINS, 512, 0, stream>>>(binned, bin_cursor, bin_base, rowptr, dn, csr);
    k_gemm_h<IN_DIM, HID_DIM><<<(N_NODES + 127) / 128, 256, 0, stream>>>(x, W1, H1h, N_NODES);

    k_agg1<<<(N_NODES / 2 + 3) / 4, 256, 0, stream>>>(H1h, rowptr, csr, dn, b1, W2, H2h);
    k_agg2m<<<(N_NODES / 2 + 3) / 4, 256, 0, stream>>>((const uint*)H2h, rowptr, csr, dn, b2,
                                                       Wp1, bp1, Wp2, bp2,
                                                       out, out + (size_t)N_NODES * OUT_DIM);
}